// Round 13
// baseline (68.632 us; speedup 1.0000x reference)
//
#include <hip/hip_runtime.h>
#include <math.h>

// TrackCrossAttention (R12 kprep/kG; k3 redesigned for contiguous track streaming,
// launched TWICE as an in-graph duration probe — idempotent, deterministic).
//   wqkT[j=h*64+d][i] = sum_e wq[i][h*64+e]*wk[d][h*64+e]   (bf16, transposed)
//   bqk[h*64+d]       = sum_e bq[h*64+e]*wk[d][h*64+e]
//   wvoT[j][h*64+d]   = sum_e wv[d][h*64+e]*wo[h*64+e][j]   (bf16, transposed)
//   bvo[j]            = sum_e bv[e]*wo[e][j] + bo[j]

#define NTOK 8192

typedef __attribute__((ext_vector_type(8))) short short8;
typedef __attribute__((ext_vector_type(8))) unsigned short ushort8;
typedef __attribute__((ext_vector_type(4))) unsigned short ushort4v;
typedef __attribute__((ext_vector_type(4))) float f32x4;

__device__ __forceinline__ unsigned short f2bf(float f) {
    unsigned int u = __float_as_uint(f);
    unsigned int r = (u + 0x7fffu + ((u >> 16) & 1u)) >> 16;
    return (unsigned short)r;
}
__device__ __forceinline__ float bf2f(unsigned short s) {
    return __uint_as_float(((unsigned int)s) << 16);
}

__device__ __forceinline__ void gl_lds16(const void* g, void* l) {
    __builtin_amdgcn_global_load_lds(
        (const __attribute__((address_space(1))) unsigned int*)g,
        (__attribute__((address_space(3))) unsigned int*)l,
        16, 0, 0);
}

// ---------------- fused prep: weight folding + RMSNorm ----------------

__global__ __launch_bounds__(256) void kprep(
    const float* __restrict__ x, const float* __restrict__ nscale,
    const float* __restrict__ wq, const float* __restrict__ bq,
    const float* __restrict__ wk, const float* __restrict__ wv,
    const float* __restrict__ bv, const float* __restrict__ wo,
    const float* __restrict__ bo,
    unsigned short* __restrict__ wqkT, float* __restrict__ bqk,
    unsigned short* __restrict__ wvoT, float* __restrict__ bvo,
    unsigned short* __restrict__ xnb)
{
    const int bid = blockIdx.x;
    const int t = threadIdx.x;
    if (bid < 64) {
        __shared__ float wkL[64][65];
        __shared__ float wqL[64][65];
        const int h = bid >> 3;
        const int i0 = (bid & 7) * 64;
        #pragma unroll
        for (int i = 0; i < 16; ++i) {
            const int idx = t + i * 256;
            const int d = idx >> 6, e = idx & 63;
            wkL[d][e] = wk[(size_t)d * 512 + h * 64 + e];
            wqL[d][e] = wq[(size_t)(i0 + d) * 512 + h * 64 + e];
        }
        __syncthreads();
        const int d = t & 63, ig = t >> 6;
        float acc[16];
        #pragma unroll
        for (int ii = 0; ii < 16; ++ii) acc[ii] = 0.f;
        for (int e = 0; e < 64; ++e) {
            const float kv = wkL[d][e];
            #pragma unroll
            for (int ii = 0; ii < 16; ++ii)
                acc[ii] += kv * wqL[ig * 16 + ii][e];
        }
        #pragma unroll
        for (int ii = 0; ii < 16; ++ii)
            wqkT[(size_t)(h * 64 + d) * 512 + i0 + ig * 16 + ii] = f2bf(acc[ii]);
        if (((bid & 7) == 0) && ig == 0) {
            float a = 0.f;
            #pragma unroll
            for (int e = 0; e < 64; ++e) a += bq[h * 64 + e] * wkL[d][e];
            bqk[h * 64 + d] = a;
        }
    } else if (bid < 128) {
        __shared__ float wvL[64][65];
        __shared__ float woL[64][65];
        const int b2 = bid - 64;
        const int h = b2 >> 3;
        const int j0 = (b2 & 7) * 64;
        #pragma unroll
        for (int i = 0; i < 16; ++i) {
            const int idx = t + i * 256;
            const int a = idx >> 6, b = idx & 63;
            wvL[a][b] = wv[(size_t)a * 512 + h * 64 + b];
            woL[a][b] = wo[(size_t)(h * 64 + a) * 512 + j0 + b];
        }
        __syncthreads();
        const int jloc = t & 63, dg = t >> 6;
        float acc[16];
        #pragma unroll
        for (int dd = 0; dd < 16; ++dd) acc[dd] = 0.f;
        for (int e = 0; e < 64; ++e) {
            const float b = woL[e][jloc];
            #pragma unroll
            for (int dd = 0; dd < 16; ++dd)
                acc[dd] += wvL[dg * 16 + dd][e] * b;
        }
        #pragma unroll
        for (int dd = 0; dd < 16; ++dd)
            wvoT[(size_t)(j0 + jloc) * 512 + h * 64 + dg * 16 + dd] = f2bf(acc[dd]);
    } else if (bid < 192) {
        const int b3 = bid - 128;
        const int j = b3 * 8 + (t >> 5);
        const int l = t & 31;
        float p = 0.f;
        #pragma unroll 4
        for (int e = l; e < 512; e += 32) p += bv[e] * wo[(size_t)e * 512 + j];
        #pragma unroll
        for (int m = 1; m < 32; m <<= 1) p += __shfl_xor(p, m, 64);
        if (l == 0) bvo[j] = bo[j] + p;
    } else {
        const int row = (bid - 192) * 4 + (t >> 6);
        const int lane = t & 63;
        const float* xr = x + (size_t)row * 512 + lane * 8;
        const float4 v0 = *reinterpret_cast<const float4*>(xr);
        const float4 v1 = *reinterpret_cast<const float4*>(xr + 4);
        float s = v0.x*v0.x + v0.y*v0.y + v0.z*v0.z + v0.w*v0.w
                + v1.x*v1.x + v1.y*v1.y + v1.z*v1.z + v1.w*v1.w;
        #pragma unroll
        for (int m = 1; m < 64; m <<= 1) s += __shfl_xor(s, m, 64);
        const float r = rsqrtf(s * (1.f / 512.f) + 1e-6f);
        const float4 s0 = *reinterpret_cast<const float4*>(nscale + lane * 8);
        const float4 s1 = *reinterpret_cast<const float4*>(nscale + lane * 8 + 4);
        ushort8 o;
        o[0] = f2bf(v0.x * r * s0.x); o[1] = f2bf(v0.y * r * s0.y);
        o[2] = f2bf(v0.z * r * s0.z); o[3] = f2bf(v0.w * r * s0.w);
        o[4] = f2bf(v1.x * r * s1.x); o[5] = f2bf(v1.y * r * s1.y);
        o[6] = f2bf(v1.z * r * s1.z); o[7] = f2bf(v1.w * r * s1.w);
        *reinterpret_cast<ushort8*>(xnb + (size_t)row * 512 + lane * 8) = o;
    }
}

// ---------------- MFMA GEMM: [8192x512] x [512x512] ----------------

template<int MODE>
__global__ __launch_bounds__(256) void kG(
    const unsigned short* __restrict__ A,
    const unsigned short* __restrict__ Bt,
    const float* __restrict__ bias,
    const float* __restrict__ resid,
    void* __restrict__ outp)
{
    __shared__ __align__(16) unsigned short Asm[2][128 * 64];
    __shared__ __align__(16) unsigned short Bsm[2][64 * 64];
    const int tid = threadIdx.x;
    const int hw = blockIdx.x;
    const int logical = (hw & 7) * 64 + (hw >> 3);
    const int mt = logical >> 3, nt = logical & 7;
    const int tok0 = mt * 128, n0 = nt * 64;
    const int w = tid >> 6, lane = tid & 63;
    const int wr = w >> 1, wc = w & 1;
    const int lrow = lane & 15, lk = lane >> 4;

    float pb[2];
    float rr[2][4][4];
    #pragma unroll
    for (int n = 0; n < 2; ++n) {
        const int ocol = n0 + wc * 32 + n * 16 + lrow;
        pb[n] = bias[ocol];
        if (MODE == 1) {
            #pragma unroll
            for (int m = 0; m < 4; ++m)
                #pragma unroll
                for (int r = 0; r < 4; ++r) {
                    const int orow = tok0 + wr * 64 + m * 16 + lk * 4 + r;
                    rr[n][m][r] = resid[(size_t)orow * 512 + ocol];
                }
        }
    }

    const int srowA[4] = { (tid + 0) >> 3, (tid + 256) >> 3, (tid + 512) >> 3, (tid + 768) >> 3 };
    const int sc8 = tid & 7;

    auto STAGE = [&](int buf, int k0) {
        #pragma unroll
        for (int i = 0; i < 4; ++i) {
            const int f = tid + i * 256;
            const int row = srowA[i];
            const int c8s = sc8 ^ (row & 7);
            gl_lds16(A + (size_t)(tok0 + row) * 512 + k0 + c8s * 8,
                     (char*)&Asm[buf][0] + f * 16);
        }
        #pragma unroll
        for (int i = 0; i < 2; ++i) {
            const int f = tid + i * 256;
            const int row = f >> 3;
            const int c8s = sc8 ^ (row & 7);
            gl_lds16(Bt + (size_t)(n0 + row) * 512 + k0 + c8s * 8,
                     (char*)&Bsm[buf][0] + f * 16);
        }
    };

    f32x4 acc[4][2] = {};
    STAGE(0, 0);
    STAGE(1, 64);
    for (int it = 0; it < 8; ++it) {
        const int cur = it & 1;
        if (it < 7) asm volatile("s_waitcnt vmcnt(6)" ::: "memory");
        else        asm volatile("s_waitcnt vmcnt(0)" ::: "memory");
        __builtin_amdgcn_s_barrier();
        __builtin_amdgcn_sched_barrier(0);
        #pragma unroll
        for (int kk = 0; kk < 2; ++kk) {
            short8 a[4], b[2];
            #pragma unroll
            for (int m = 0; m < 4; ++m) {
                const int r = wr * 64 + m * 16 + lrow;
                const int byte = (r * 128 + kk * 64 + lk * 16) ^ ((r & 7) << 4);
                a[m] = *reinterpret_cast<const short8*>((const char*)&Asm[cur][0] + byte);
            }
            #pragma unroll
            for (int n = 0; n < 2; ++n) {
                const int r = wc * 32 + n * 16 + lrow;
                const int byte = (r * 128 + kk * 64 + lk * 16) ^ ((r & 7) << 4);
                b[n] = *reinterpret_cast<const short8*>((const char*)&Bsm[cur][0] + byte);
            }
            #pragma unroll
            for (int m = 0; m < 4; ++m)
                #pragma unroll
                for (int n = 0; n < 2; ++n)
                    acc[m][n] = __builtin_amdgcn_mfma_f32_16x16x32_bf16(
                        a[m], b[n], acc[m][n], 0, 0, 0);
        }
        __builtin_amdgcn_sched_barrier(0);
        __builtin_amdgcn_s_barrier();
        __builtin_amdgcn_sched_barrier(0);
        if (it < 6) STAGE(cur, (it + 2) * 64);
    }
    #pragma unroll
    for (int n = 0; n < 2; ++n) {
        const int ocol = n0 + wc * 32 + n * 16 + lrow;
        #pragma unroll
        for (int m = 0; m < 4; ++m) {
            #pragma unroll
            for (int r = 0; r < 4; ++r) {
                const int orow = tok0 + wr * 64 + m * 16 + lk * 4 + r;
                float v = acc[m][n][r] + pb[n];
                if (MODE == 0) {
                    ((unsigned short*)outp)[(size_t)orow * 512 + ocol] = f2bf(v);
                } else {
                    v += rr[n][m][r];
                    ((float*)outp)[(size_t)orow * 512 + ocol] = v;
                }
            }
        }
    }
}

// ---------------- attention: 16 tok/block, contiguous track streaming ----------------
// Per block: tf tile (16 t x 16 tok x 256B) staged as 16 contiguous 4-KB streams;
// qw 16 KB. One vmcnt(0)+barrier; all compute intra-wave (shfl softmax/PV).

__global__ __launch_bounds__(256) void k3_attn(
    const float* __restrict__ track, const unsigned short* __restrict__ qwb,
    unsigned short* __restrict__ wtfb)
{
    __shared__ __align__(16) char tfL[65536];   // [t][tk][16 chunks], src-swizzled
    __shared__ __align__(16) char qwL[16384];   // [tk][64 chunks], src-swizzled
    const int tid = threadIdx.x;
    const int hw = blockIdx.x;                  // 512 blocks
    const int logical = (hw & 7) * 64 + (hw >> 3);   // XCD-chunked, bijective
    const int tok0 = logical * 16;
    const int b = tok0 >> 12;                   // constant in block (16 | 4096)
    const int c0 = tok0 & 4095;

    // qw: 1024 chunks (4/thread), row-wise 1KB contiguous, low3-XOR src swizzle
    #pragma unroll
    for (int i = 0; i < 4; ++i) {
        const int f = tid + i * 256;
        const int tk = f >> 6, ch = f & 63;
        const int chs = ch ^ (tk & 7);
        gl_lds16(qwb + (size_t)(tok0 + tk) * 512 + chs * 8, qwL + f * 16);
    }
    // tf: 4096 chunks (16/thread); each wave-instr covers 1KB contiguous
    #pragma unroll
    for (int i = 0; i < 16; ++i) {
        const int f = tid + i * 256;
        const int t = f >> 8, tk = (f >> 4) & 15, ch = f & 15;
        const int chs = ch ^ ((t + tk) & 7);
        gl_lds16(track + ((size_t)(b * 16 + t) * 4096 + (c0 + tk)) * 64 + chs * 4,
                 tfL + f * 16);
    }
    asm volatile("s_waitcnt vmcnt(0)" ::: "memory");
    __builtin_amdgcn_s_barrier();
    __builtin_amdgcn_sched_barrier(0);

    const int tok = tid >> 4;       // 0..15
    const int t = tid & 15;         // logits role: slot t; PV role: d-quad t
    const int lane = tid & 63;

    // cache tf row (t, tok): 16 float4
    float4 tfr[16];
    {
        const int row = (t * 16 + tok) * 256;
        const int s = (t + tok) & 7;
        #pragma unroll
        for (int q = 0; q < 16; ++q)
            tfr[q] = *reinterpret_cast<const float4*>(tfL + row + ((q ^ s) << 4));
    }
    // 8 head-logits + softmax weights
    float pw8[8];
    {
        const int qbase = tok * 1024;
        const int sq = tok & 7;
        #pragma unroll
        for (int h = 0; h < 8; ++h) {
            float a = 0.f;
            #pragma unroll
            for (int qc = 0; qc < 8; ++qc) {
                const ushort8 qv = *reinterpret_cast<const ushort8*>(
                    qwL + qbase + (((h * 8 + qc) ^ sq) << 4));
                const float4 t0 = tfr[qc * 2], t1 = tfr[qc * 2 + 1];
                a += bf2f(qv[0])*t0.x + bf2f(qv[1])*t0.y + bf2f(qv[2])*t0.z + bf2f(qv[3])*t0.w
                   + bf2f(qv[4])*t1.x + bf2f(qv[5])*t1.y + bf2f(qv[6])*t1.z + bf2f(qv[7])*t1.w;
            }
            float lg = a * 0.125f;   // 1/sqrt(64)
            float mx = lg;
            #pragma unroll
            for (int m = 1; m < 16; m <<= 1) mx = fmaxf(mx, __shfl_xor(mx, m, 64));
            const float ev = __expf(lg - mx);
            float sm = ev;
            #pragma unroll
            for (int m = 1; m < 16; m <<= 1) sm += __shfl_xor(sm, m, 64);
            pw8[h] = ev / sm;
        }
    }
    // PV: thread (tok, dq=t) accumulates d = t*4..t*4+3 for all 8 heads
    float o[8][4];
    #pragma unroll
    for (int h = 0; h < 8; ++h)
        #pragma unroll
        for (int j = 0; j < 4; ++j) o[h][j] = 0.f;
    #pragma unroll
    for (int tt = 0; tt < 16; ++tt) {
        const int row = (tt * 16 + tok) * 256;
        const float4 tv = *reinterpret_cast<const float4*>(
            tfL + row + ((t ^ ((tt + tok) & 7)) << 4));
        #pragma unroll
        for (int h = 0; h < 8; ++h) {
            const float wt = __shfl(pw8[h], (lane & 48) + tt, 64);
            o[h][0] += wt * tv.x; o[h][1] += wt * tv.y;
            o[h][2] += wt * tv.z; o[h][3] += wt * tv.w;
        }
    }
    const int token = tok0 + tok;
    #pragma unroll
    for (int h = 0; h < 8; ++h) {
        ushort4v ov;
        ov[0] = f2bf(o[h][0]); ov[1] = f2bf(o[h][1]);
        ov[2] = f2bf(o[h][2]); ov[3] = f2bf(o[h][3]);
        *reinterpret_cast<ushort4v*>(wtfb + (size_t)token * 512 + h * 64 + t * 4) = ov;
    }
}

extern "C" void kernel_launch(void* const* d_in, const int* in_sizes, int n_in,
                              void* d_out, int out_size, void* d_ws, size_t ws_size,
                              hipStream_t stream) {
    const float* x      = (const float*)d_in[0];
    const float* track  = (const float*)d_in[1];
    const float* nscale = (const float*)d_in[2];
    const float* wq     = (const float*)d_in[3];
    const float* bq     = (const float*)d_in[4];
    const float* wk     = (const float*)d_in[5];
    // d_in[6] = bk: constant over t per head -> softmax-invariant, omitted exactly
    const float* wv     = (const float*)d_in[7];
    const float* bv     = (const float*)d_in[8];
    const float* wo     = (const float*)d_in[9];
    const float* bo     = (const float*)d_in[10];
    float* buf = (float*)d_out;

    char* ws = (char*)d_ws;
    unsigned short* xnb  = (unsigned short*)ws;                // 8 MB (xn)
    unsigned short* qwb  = (unsigned short*)(ws + 8388608);    // 8 MB (qw bf16)
    unsigned short* wtfb = (unsigned short*)(ws + 16777216);   // 8 MB (wtf bf16)
    unsigned short* wqkT = (unsigned short*)(ws + 25165824);   // 512 KB
    unsigned short* wvoT = (unsigned short*)(ws + 25690112);   // 512 KB
    float* bqk = (float*)(ws + 26214400);                      // 2 KB
    float* bvo = (float*)(ws + 26216448);                      // 2 KB

    kprep<<<192 + NTOK / 4, 256, 0, stream>>>(x, nscale, wq, bq, wk, wv, bv, wo, bo,
                                              wqkT, bqk, wvoT, bvo, xnb);
    kG<0><<<512, 256, 0, stream>>>(xnb, wqkT, bqk, nullptr, qwb);
    // k3 launched TWICE (idempotent probe): dur delta vs next round isolates its cost.
    k3_attn<<<512, 256, 0, stream>>>(track, qwb, wtfb);
    k3_attn<<<512, 256, 0, stream>>>(track, qwb, wtfb);
    kG<1><<<512, 256, 0, stream>>>(wtfb, wvoT, bvo, x, buf);
}

// Round 14
// 52.775 us; speedup vs baseline: 1.3005x; 1.3005x over previous
//
#include <hip/hip_runtime.h>
#include <math.h>

// TrackCrossAttention — XCD-aligned producer/consumer pipeline:
// XCD k owns token rows with mt%8==k across ALL kernels, so xnb/qwb/wtfb
// stay in the owning XCD's L2 (1MB slice each + 1MB B < 4MB).
//   wqkT[j=h*64+d][i] = sum_e wq[i][h*64+e]*wk[d][h*64+e]   (bf16, transposed)
//   bqk[h*64+d]       = sum_e bq[h*64+e]*wk[d][h*64+e]
//   wvoT[j][h*64+d]   = sum_e wv[d][h*64+e]*wo[h*64+e][j]   (bf16, transposed)
//   bvo[j]            = sum_e bv[e]*wo[e][j] + bo[j]

#define NTOK 8192

typedef __attribute__((ext_vector_type(8))) short short8;
typedef __attribute__((ext_vector_type(8))) unsigned short ushort8;
typedef __attribute__((ext_vector_type(4))) unsigned short ushort4v;
typedef __attribute__((ext_vector_type(4))) float f32x4;

__device__ __forceinline__ unsigned short f2bf(float f) {
    unsigned int u = __float_as_uint(f);
    unsigned int r = (u + 0x7fffu + ((u >> 16) & 1u)) >> 16;
    return (unsigned short)r;
}
__device__ __forceinline__ float bf2f(unsigned short s) {
    return __uint_as_float(((unsigned int)s) << 16);
}

__device__ __forceinline__ void gl_lds16(const void* g, void* l) {
    __builtin_amdgcn_global_load_lds(
        (const __attribute__((address_space(1))) unsigned int*)g,
        (__attribute__((address_space(3))) unsigned int*)l,
        16, 0, 0);
}

// ---------------- fused prep: weight folding + RMSNorm ----------------

__global__ __launch_bounds__(256) void kprep(
    const float* __restrict__ x, const float* __restrict__ nscale,
    const float* __restrict__ wq, const float* __restrict__ bq,
    const float* __restrict__ wk, const float* __restrict__ wv,
    const float* __restrict__ bv, const float* __restrict__ wo,
    const float* __restrict__ bo,
    unsigned short* __restrict__ wqkT, float* __restrict__ bqk,
    unsigned short* __restrict__ wvoT, float* __restrict__ bvo,
    unsigned short* __restrict__ xnb)
{
    const int bid = blockIdx.x;
    const int t = threadIdx.x;
    if (bid < 64) {
        __shared__ float wkL[64][65];
        __shared__ float wqL[64][65];
        const int h = bid >> 3;
        const int i0 = (bid & 7) * 64;
        #pragma unroll
        for (int i = 0; i < 16; ++i) {
            const int idx = t + i * 256;
            const int d = idx >> 6, e = idx & 63;
            wkL[d][e] = wk[(size_t)d * 512 + h * 64 + e];
            wqL[d][e] = wq[(size_t)(i0 + d) * 512 + h * 64 + e];
        }
        __syncthreads();
        const int d = t & 63, ig = t >> 6;
        float acc[16];
        #pragma unroll
        for (int ii = 0; ii < 16; ++ii) acc[ii] = 0.f;
        for (int e = 0; e < 64; ++e) {
            const float kv = wkL[d][e];
            #pragma unroll
            for (int ii = 0; ii < 16; ++ii)
                acc[ii] += kv * wqL[ig * 16 + ii][e];
        }
        #pragma unroll
        for (int ii = 0; ii < 16; ++ii)
            wqkT[(size_t)(h * 64 + d) * 512 + i0 + ig * 16 + ii] = f2bf(acc[ii]);
        if (((bid & 7) == 0) && ig == 0) {
            float a = 0.f;
            #pragma unroll
            for (int e = 0; e < 64; ++e) a += bq[h * 64 + e] * wkL[d][e];
            bqk[h * 64 + d] = a;
        }
    } else if (bid < 128) {
        __shared__ float wvL[64][65];
        __shared__ float woL[64][65];
        const int b2 = bid - 64;
        const int h = b2 >> 3;
        const int j0 = (b2 & 7) * 64;
        #pragma unroll
        for (int i = 0; i < 16; ++i) {
            const int idx = t + i * 256;
            const int a = idx >> 6, b = idx & 63;
            wvL[a][b] = wv[(size_t)a * 512 + h * 64 + b];
            woL[a][b] = wo[(size_t)(h * 64 + a) * 512 + j0 + b];
        }
        __syncthreads();
        const int jloc = t & 63, dg = t >> 6;
        float acc[16];
        #pragma unroll
        for (int dd = 0; dd < 16; ++dd) acc[dd] = 0.f;
        for (int e = 0; e < 64; ++e) {
            const float b = woL[e][jloc];
            #pragma unroll
            for (int dd = 0; dd < 16; ++dd)
                acc[dd] += wvL[dg * 16 + dd][e] * b;
        }
        #pragma unroll
        for (int dd = 0; dd < 16; ++dd)
            wvoT[(size_t)(j0 + jloc) * 512 + h * 64 + dg * 16 + dd] = f2bf(acc[dd]);
    } else if (bid < 192) {
        const int b3 = bid - 128;
        const int j = b3 * 8 + (t >> 5);
        const int l = t & 31;
        float p = 0.f;
        #pragma unroll 4
        for (int e = l; e < 512; e += 32) p += bv[e] * wo[(size_t)e * 512 + j];
        #pragma unroll
        for (int m = 1; m < 32; m <<= 1) p += __shfl_xor(p, m, 64);
        if (l == 0) bvo[j] = bo[j] + p;
    } else {
        // RMSNorm: XCD-aligned row mapping. p on XCD kx=p&7; owns rows of
        // mt in {kx, kx+8, ...}: pl = (kx + 8*(j>>5))*32 + (j&31).
        const int p = bid - 192;               // 0..2047
        const int kx = p & 7, j = p >> 3;      // j 0..255
        const int pl = (kx + 8 * (j >> 5)) * 32 + (j & 31);
        const int row = pl * 4 + (t >> 6);
        const int lane = t & 63;
        const float* xr = x + (size_t)row * 512 + lane * 8;
        const float4 v0 = *reinterpret_cast<const float4*>(xr);
        const float4 v1 = *reinterpret_cast<const float4*>(xr + 4);
        float s = v0.x*v0.x + v0.y*v0.y + v0.z*v0.z + v0.w*v0.w
                + v1.x*v1.x + v1.y*v1.y + v1.z*v1.z + v1.w*v1.w;
        #pragma unroll
        for (int m = 1; m < 64; m <<= 1) s += __shfl_xor(s, m, 64);
        const float r = rsqrtf(s * (1.f / 512.f) + 1e-6f);
        const float4 s0 = *reinterpret_cast<const float4*>(nscale + lane * 8);
        const float4 s1 = *reinterpret_cast<const float4*>(nscale + lane * 8 + 4);
        ushort8 o;
        o[0] = f2bf(v0.x * r * s0.x); o[1] = f2bf(v0.y * r * s0.y);
        o[2] = f2bf(v0.z * r * s0.z); o[3] = f2bf(v0.w * r * s0.w);
        o[4] = f2bf(v1.x * r * s1.x); o[5] = f2bf(v1.y * r * s1.y);
        o[6] = f2bf(v1.z * r * s1.z); o[7] = f2bf(v1.w * r * s1.w);
        *reinterpret_cast<ushort8*>(xnb + (size_t)row * 512 + lane * 8) = o;
    }
}

// ---------------- MFMA GEMM: [8192x512] x [512x512] ----------------
// Row-owner XCD swizzle: XCD k gets mt in {k, k+8, ...} (all nt) -> A rows
// and C rows stay in the owning XCD's L2 across the whole pipeline.

template<int MODE>
__global__ __launch_bounds__(256) void kG(
    const unsigned short* __restrict__ A,
    const unsigned short* __restrict__ Bt,
    const float* __restrict__ bias,
    const float* __restrict__ resid,
    void* __restrict__ outp)
{
    __shared__ __align__(16) unsigned short Asm[2][128 * 64];
    __shared__ __align__(16) unsigned short Bsm[2][64 * 64];
    const int tid = threadIdx.x;
    const int hw = blockIdx.x;
    const int kx = hw & 7, idx = hw >> 3;        // idx 0..63
    const int mt = kx + (idx >> 3) * 8;          // row-owner mapping
    const int nt = idx & 7;
    const int tok0 = mt * 128, n0 = nt * 64;
    const int w = tid >> 6, lane = tid & 63;
    const int wr = w >> 1, wc = w & 1;
    const int lrow = lane & 15, lk = lane >> 4;

    float pb[2];
    float rr[2][4][4];
    #pragma unroll
    for (int n = 0; n < 2; ++n) {
        const int ocol = n0 + wc * 32 + n * 16 + lrow;
        pb[n] = bias[ocol];
        if (MODE == 1) {
            #pragma unroll
            for (int m = 0; m < 4; ++m)
                #pragma unroll
                for (int r = 0; r < 4; ++r) {
                    const int orow = tok0 + wr * 64 + m * 16 + lk * 4 + r;
                    rr[n][m][r] = resid[(size_t)orow * 512 + ocol];
                }
        }
    }

    const int srowA[4] = { (tid + 0) >> 3, (tid + 256) >> 3, (tid + 512) >> 3, (tid + 768) >> 3 };
    const int sc8 = tid & 7;

    auto STAGE = [&](int buf, int k0) {          // 6 gl_lds16 per thread
        #pragma unroll
        for (int i = 0; i < 4; ++i) {
            const int f = tid + i * 256;
            const int row = srowA[i];
            const int c8s = sc8 ^ (row & 7);
            gl_lds16(A + (size_t)(tok0 + row) * 512 + k0 + c8s * 8,
                     (char*)&Asm[buf][0] + f * 16);
        }
        #pragma unroll
        for (int i = 0; i < 2; ++i) {
            const int f = tid + i * 256;
            const int row = f >> 3;
            const int c8s = sc8 ^ (row & 7);
            gl_lds16(Bt + (size_t)(n0 + row) * 512 + k0 + c8s * 8,
                     (char*)&Bsm[buf][0] + f * 16);
        }
    };

    f32x4 acc[4][2] = {};
    STAGE(0, 0);
    STAGE(1, 64);
    for (int it = 0; it < 8; ++it) {
        const int cur = it & 1;
        if (it < 7) asm volatile("s_waitcnt vmcnt(6)" ::: "memory");
        else        asm volatile("s_waitcnt vmcnt(0)" ::: "memory");
        __builtin_amdgcn_s_barrier();
        __builtin_amdgcn_sched_barrier(0);
        #pragma unroll
        for (int kk = 0; kk < 2; ++kk) {
            short8 a[4], b[2];
            #pragma unroll
            for (int m = 0; m < 4; ++m) {
                const int r = wr * 64 + m * 16 + lrow;
                const int byte = (r * 128 + kk * 64 + lk * 16) ^ ((r & 7) << 4);
                a[m] = *reinterpret_cast<const short8*>((const char*)&Asm[cur][0] + byte);
            }
            #pragma unroll
            for (int n = 0; n < 2; ++n) {
                const int r = wc * 32 + n * 16 + lrow;
                const int byte = (r * 128 + kk * 64 + lk * 16) ^ ((r & 7) << 4);
                b[n] = *reinterpret_cast<const short8*>((const char*)&Bsm[cur][0] + byte);
            }
            #pragma unroll
            for (int m = 0; m < 4; ++m)
                #pragma unroll
                for (int n = 0; n < 2; ++n)
                    acc[m][n] = __builtin_amdgcn_mfma_f32_16x16x32_bf16(
                        a[m], b[n], acc[m][n], 0, 0, 0);
        }
        __builtin_amdgcn_sched_barrier(0);
        __builtin_amdgcn_s_barrier();
        __builtin_amdgcn_sched_barrier(0);
        if (it < 6) STAGE(cur, (it + 2) * 64);
    }
    #pragma unroll
    for (int n = 0; n < 2; ++n) {
        const int ocol = n0 + wc * 32 + n * 16 + lrow;
        #pragma unroll
        for (int m = 0; m < 4; ++m) {
            #pragma unroll
            for (int r = 0; r < 4; ++r) {
                const int orow = tok0 + wr * 64 + m * 16 + lk * 4 + r;
                float v = acc[m][n][r] + pb[n];
                if (MODE == 0) {
                    ((unsigned short*)outp)[(size_t)orow * 512 + ocol] = f2bf(v);
                } else {
                    v += rr[n][m][r];
                    ((float*)outp)[(size_t)orow * 512 + ocol] = v;
                }
            }
        }
    }
}

// ---------------- attention: 16 tok/block, XCD row-owner aligned ----------------

__global__ __launch_bounds__(256) void k3_attn(
    const float* __restrict__ track, const unsigned short* __restrict__ qwb,
    unsigned short* __restrict__ wtfb)
{
    __shared__ __align__(16) char tfL[65536];   // [t][tk][16 chunks], src-swizzled
    __shared__ __align__(16) char qwL[16384];   // [tk][64 chunks], src-swizzled
    const int tid = threadIdx.x;
    const int hw = blockIdx.x;                  // 512 blocks
    const int kx = hw & 7, j = hw >> 3;         // j 0..63
    const int logical = (kx + 8 * (j >> 3)) * 8 + (j & 7);   // XCD kx owns mt%8==kx
    const int tok0 = logical * 16;
    const int b = tok0 >> 12;
    const int c0 = tok0 & 4095;

    #pragma unroll
    for (int i = 0; i < 4; ++i) {
        const int f = tid + i * 256;
        const int tk = f >> 6, ch = f & 63;
        const int chs = ch ^ (tk & 7);
        gl_lds16(qwb + (size_t)(tok0 + tk) * 512 + chs * 8, qwL + f * 16);
    }
    #pragma unroll
    for (int i = 0; i < 16; ++i) {
        const int f = tid + i * 256;
        const int t = f >> 8, tk = (f >> 4) & 15, ch = f & 15;
        const int chs = ch ^ ((t + tk) & 7);
        gl_lds16(track + ((size_t)(b * 16 + t) * 4096 + (c0 + tk)) * 64 + chs * 4,
                 tfL + f * 16);
    }
    asm volatile("s_waitcnt vmcnt(0)" ::: "memory");
    __builtin_amdgcn_s_barrier();
    __builtin_amdgcn_sched_barrier(0);

    const int tok = tid >> 4;
    const int t = tid & 15;
    const int lane = tid & 63;

    float4 tfr[16];
    {
        const int row = (t * 16 + tok) * 256;
        const int s = (t + tok) & 7;
        #pragma unroll
        for (int q = 0; q < 16; ++q)
            tfr[q] = *reinterpret_cast<const float4*>(tfL + row + ((q ^ s) << 4));
    }
    float pw8[8];
    {
        const int qbase = tok * 1024;
        const int sq = tok & 7;
        #pragma unroll
        for (int h = 0; h < 8; ++h) {
            float a = 0.f;
            #pragma unroll
            for (int qc = 0; qc < 8; ++qc) {
                const ushort8 qv = *reinterpret_cast<const ushort8*>(
                    qwL + qbase + (((h * 8 + qc) ^ sq) << 4));
                const float4 t0 = tfr[qc * 2], t1 = tfr[qc * 2 + 1];
                a += bf2f(qv[0])*t0.x + bf2f(qv[1])*t0.y + bf2f(qv[2])*t0.z + bf2f(qv[3])*t0.w
                   + bf2f(qv[4])*t1.x + bf2f(qv[5])*t1.y + bf2f(qv[6])*t1.z + bf2f(qv[7])*t1.w;
            }
            float lg = a * 0.125f;
            float mx = lg;
            #pragma unroll
            for (int m = 1; m < 16; m <<= 1) mx = fmaxf(mx, __shfl_xor(mx, m, 64));
            const float ev = __expf(lg - mx);
            float sm = ev;
            #pragma unroll
            for (int m = 1; m < 16; m <<= 1) sm += __shfl_xor(sm, m, 64);
            pw8[h] = ev / sm;
        }
    }
    float o[8][4];
    #pragma unroll
    for (int h = 0; h < 8; ++h)
        #pragma unroll
        for (int jj = 0; jj < 4; ++jj) o[h][jj] = 0.f;
    #pragma unroll
    for (int tt = 0; tt < 16; ++tt) {
        const int row = (tt * 16 + tok) * 256;
        const float4 tv = *reinterpret_cast<const float4*>(
            tfL + row + ((t ^ ((tt + tok) & 7)) << 4));
        #pragma unroll
        for (int h = 0; h < 8; ++h) {
            const float wt = __shfl(pw8[h], (lane & 48) + tt, 64);
            o[h][0] += wt * tv.x; o[h][1] += wt * tv.y;
            o[h][2] += wt * tv.z; o[h][3] += wt * tv.w;
        }
    }
    const int token = tok0 + tok;
    #pragma unroll
    for (int h = 0; h < 8; ++h) {
        ushort4v ov;
        ov[0] = f2bf(o[h][0]); ov[1] = f2bf(o[h][1]);
        ov[2] = f2bf(o[h][2]); ov[3] = f2bf(o[h][3]);
        *reinterpret_cast<ushort4v*>(wtfb + (size_t)token * 512 + h * 64 + t * 4) = ov;
    }
}

extern "C" void kernel_launch(void* const* d_in, const int* in_sizes, int n_in,
                              void* d_out, int out_size, void* d_ws, size_t ws_size,
                              hipStream_t stream) {
    const float* x      = (const float*)d_in[0];
    const float* track  = (const float*)d_in[1];
    const float* nscale = (const float*)d_in[2];
    const float* wq     = (const float*)d_in[3];
    const float* bq     = (const float*)d_in[4];
    const float* wk     = (const float*)d_in[5];
    // d_in[6] = bk: constant over t per head -> softmax-invariant, omitted exactly
    const float* wv     = (const float*)d_in[7];
    const float* bv     = (const float*)d_in[8];
    const float* wo     = (const float*)d_in[9];
    const float* bo     = (const float*)d_in[10];
    float* buf = (float*)d_out;

    char* ws = (char*)d_ws;
    unsigned short* xnb  = (unsigned short*)ws;                // 8 MB (xn)
    unsigned short* qwb  = (unsigned short*)(ws + 8388608);    // 8 MB (qw bf16)
    unsigned short* wtfb = (unsigned short*)(ws + 16777216);   // 8 MB (wtf bf16)
    unsigned short* wqkT = (unsigned short*)(ws + 25165824);   // 512 KB
    unsigned short* wvoT = (unsigned short*)(ws + 25690112);   // 512 KB
    float* bqk = (float*)(ws + 26214400);                      // 2 KB
    float* bvo = (float*)(ws + 26216448);                      // 2 KB

    kprep<<<192 + NTOK / 4, 256, 0, stream>>>(x, nscale, wq, bq, wk, wv, bv, wo, bo,
                                              wqkT, bqk, wvoT, bvo, xnb);
    kG<0><<<512, 256, 0, stream>>>(xnb, wqkT, bqk, nullptr, qwb);
    k3_attn<<<512, 256, 0, stream>>>(track, qwb, wtfb);
    kG<1><<<512, 256, 0, stream>>>(wtfb, wvoT, bvo, x, buf);
}

// Round 16
// 51.271 us; speedup vs baseline: 1.3386x; 1.0293x over previous
//
#include <hip/hip_runtime.h>
#include <math.h>

// TrackCrossAttention (R12/R14 passing structure; k3 -> 8 tok/block, 40KB LDS,
// 4 blocks/CU for latency hiding):
//   wqkT[j=h*64+d][i] = sum_e wq[i][h*64+e]*wk[d][h*64+e]   (bf16, transposed)
//   bqk[h*64+d]       = sum_e bq[h*64+e]*wk[d][h*64+e]
//   wvoT[j][h*64+d]   = sum_e wv[d][h*64+e]*wo[h*64+e][j]   (bf16, transposed)
//   bvo[j]            = sum_e bv[e]*wo[e][j] + bo[j]

#define NTOK 8192

typedef __attribute__((ext_vector_type(8))) short short8;
typedef __attribute__((ext_vector_type(8))) unsigned short ushort8;
typedef __attribute__((ext_vector_type(4))) unsigned short ushort4v;
typedef __attribute__((ext_vector_type(4))) float f32x4;

__device__ __forceinline__ unsigned short f2bf(float f) {
    unsigned int u = __float_as_uint(f);
    unsigned int r = (u + 0x7fffu + ((u >> 16) & 1u)) >> 16;
    return (unsigned short)r;
}
__device__ __forceinline__ float bf2f(unsigned short s) {
    return __uint_as_float(((unsigned int)s) << 16);
}

__device__ __forceinline__ void gl_lds16(const void* g, void* l) {
    __builtin_amdgcn_global_load_lds(
        (const __attribute__((address_space(1))) unsigned int*)g,
        (__attribute__((address_space(3))) unsigned int*)l,
        16, 0, 0);
}

// ---------------- fused prep: weight folding + RMSNorm ----------------

__global__ __launch_bounds__(256) void kprep(
    const float* __restrict__ x, const float* __restrict__ nscale,
    const float* __restrict__ wq, const float* __restrict__ bq,
    const float* __restrict__ wk, const float* __restrict__ wv,
    const float* __restrict__ bv, const float* __restrict__ wo,
    const float* __restrict__ bo,
    unsigned short* __restrict__ wqkT, float* __restrict__ bqk,
    unsigned short* __restrict__ wvoT, float* __restrict__ bvo,
    unsigned short* __restrict__ xnb)
{
    const int bid = blockIdx.x;
    const int t = threadIdx.x;
    if (bid < 64) {
        __shared__ float wkL[64][65];
        __shared__ float wqL[64][65];
        const int h = bid >> 3;
        const int i0 = (bid & 7) * 64;
        #pragma unroll
        for (int i = 0; i < 16; ++i) {
            const int idx = t + i * 256;
            const int d = idx >> 6, e = idx & 63;
            wkL[d][e] = wk[(size_t)d * 512 + h * 64 + e];
            wqL[d][e] = wq[(size_t)(i0 + d) * 512 + h * 64 + e];
        }
        __syncthreads();
        const int d = t & 63, ig = t >> 6;
        float acc[16];
        #pragma unroll
        for (int ii = 0; ii < 16; ++ii) acc[ii] = 0.f;
        for (int e = 0; e < 64; ++e) {
            const float kv = wkL[d][e];
            #pragma unroll
            for (int ii = 0; ii < 16; ++ii)
                acc[ii] += kv * wqL[ig * 16 + ii][e];
        }
        #pragma unroll
        for (int ii = 0; ii < 16; ++ii)
            wqkT[(size_t)(h * 64 + d) * 512 + i0 + ig * 16 + ii] = f2bf(acc[ii]);
        if (((bid & 7) == 0) && ig == 0) {
            float a = 0.f;
            #pragma unroll
            for (int e = 0; e < 64; ++e) a += bq[h * 64 + e] * wkL[d][e];
            bqk[h * 64 + d] = a;
        }
    } else if (bid < 128) {
        __shared__ float wvL[64][65];
        __shared__ float woL[64][65];
        const int b2 = bid - 64;
        const int h = b2 >> 3;
        const int j0 = (b2 & 7) * 64;
        #pragma unroll
        for (int i = 0; i < 16; ++i) {
            const int idx = t + i * 256;
            const int a = idx >> 6, b = idx & 63;
            wvL[a][b] = wv[(size_t)a * 512 + h * 64 + b];
            woL[a][b] = wo[(size_t)(h * 64 + a) * 512 + j0 + b];
        }
        __syncthreads();
        const int jloc = t & 63, dg = t >> 6;
        float acc[16];
        #pragma unroll
        for (int dd = 0; dd < 16; ++dd) acc[dd] = 0.f;
        for (int e = 0; e < 64; ++e) {
            const float b = woL[e][jloc];
            #pragma unroll
            for (int dd = 0; dd < 16; ++dd)
                acc[dd] += wvL[dg * 16 + dd][e] * b;
        }
        #pragma unroll
        for (int dd = 0; dd < 16; ++dd)
            wvoT[(size_t)(j0 + jloc) * 512 + h * 64 + dg * 16 + dd] = f2bf(acc[dd]);
    } else if (bid < 192) {
        const int b3 = bid - 128;
        const int j = b3 * 8 + (t >> 5);
        const int l = t & 31;
        float p = 0.f;
        #pragma unroll 4
        for (int e = l; e < 512; e += 32) p += bv[e] * wo[(size_t)e * 512 + j];
        #pragma unroll
        for (int m = 1; m < 32; m <<= 1) p += __shfl_xor(p, m, 64);
        if (l == 0) bvo[j] = bo[j] + p;
    } else {
        const int row = (bid - 192) * 4 + (t >> 6);
        const int lane = t & 63;
        const float* xr = x + (size_t)row * 512 + lane * 8;
        const float4 v0 = *reinterpret_cast<const float4*>(xr);
        const float4 v1 = *reinterpret_cast<const float4*>(xr + 4);
        float s = v0.x*v0.x + v0.y*v0.y + v0.z*v0.z + v0.w*v0.w
                + v1.x*v1.x + v1.y*v1.y + v1.z*v1.z + v1.w*v1.w;
        #pragma unroll
        for (int m = 1; m < 64; m <<= 1) s += __shfl_xor(s, m, 64);
        const float r = rsqrtf(s * (1.f / 512.f) + 1e-6f);
        const float4 s0 = *reinterpret_cast<const float4*>(nscale + lane * 8);
        const float4 s1 = *reinterpret_cast<const float4*>(nscale + lane * 8 + 4);
        ushort8 o;
        o[0] = f2bf(v0.x * r * s0.x); o[1] = f2bf(v0.y * r * s0.y);
        o[2] = f2bf(v0.z * r * s0.z); o[3] = f2bf(v0.w * r * s0.w);
        o[4] = f2bf(v1.x * r * s1.x); o[5] = f2bf(v1.y * r * s1.y);
        o[6] = f2bf(v1.z * r * s1.z); o[7] = f2bf(v1.w * r * s1.w);
        *reinterpret_cast<ushort8*>(xnb + (size_t)row * 512 + lane * 8) = o;
    }
}

// ---------------- MFMA GEMM: [8192x512] x [512x512] ----------------
// 128x64 tile, BK=64, 2-deep counted-vmcnt pipeline.

template<int MODE>
__global__ __launch_bounds__(256) void kG(
    const unsigned short* __restrict__ A,
    const unsigned short* __restrict__ Bt,
    const float* __restrict__ bias,
    const float* __restrict__ resid,
    void* __restrict__ outp)
{
    __shared__ __align__(16) unsigned short Asm[2][128 * 64];
    __shared__ __align__(16) unsigned short Bsm[2][64 * 64];
    const int tid = threadIdx.x;
    const int hw = blockIdx.x;
    const int logical = (hw & 7) * 64 + (hw >> 3);
    const int mt = logical >> 3, nt = logical & 7;
    const int tok0 = mt * 128, n0 = nt * 64;
    const int w = tid >> 6, lane = tid & 63;
    const int wr = w >> 1, wc = w & 1;
    const int lrow = lane & 15, lk = lane >> 4;

    float pb[2];
    float rr[2][4][4];
    #pragma unroll
    for (int n = 0; n < 2; ++n) {
        const int ocol = n0 + wc * 32 + n * 16 + lrow;
        pb[n] = bias[ocol];
        if (MODE == 1) {
            #pragma unroll
            for (int m = 0; m < 4; ++m)
                #pragma unroll
                for (int r = 0; r < 4; ++r) {
                    const int orow = tok0 + wr * 64 + m * 16 + lk * 4 + r;
                    rr[n][m][r] = resid[(size_t)orow * 512 + ocol];
                }
        }
    }

    const int srowA[4] = { (tid + 0) >> 3, (tid + 256) >> 3, (tid + 512) >> 3, (tid + 768) >> 3 };
    const int sc8 = tid & 7;

    auto STAGE = [&](int buf, int k0) {      // 6 gl_lds16 per thread
        #pragma unroll
        for (int i = 0; i < 4; ++i) {
            const int f = tid + i * 256;
            const int row = srowA[i];
            const int c8s = sc8 ^ (row & 7);
            gl_lds16(A + (size_t)(tok0 + row) * 512 + k0 + c8s * 8,
                     (char*)&Asm[buf][0] + f * 16);
        }
        #pragma unroll
        for (int i = 0; i < 2; ++i) {
            const int f = tid + i * 256;
            const int row = f >> 3;
            const int c8s = sc8 ^ (row & 7);
            gl_lds16(Bt + (size_t)(n0 + row) * 512 + k0 + c8s * 8,
                     (char*)&Bsm[buf][0] + f * 16);
        }
    };

    f32x4 acc[4][2] = {};
    STAGE(0, 0);
    STAGE(1, 64);
    for (int it = 0; it < 8; ++it) {
        const int cur = it & 1;
        if (it < 7) asm volatile("s_waitcnt vmcnt(6)" ::: "memory");
        else        asm volatile("s_waitcnt vmcnt(0)" ::: "memory");
        __builtin_amdgcn_s_barrier();
        __builtin_amdgcn_sched_barrier(0);
        #pragma unroll
        for (int kk = 0; kk < 2; ++kk) {
            short8 a[4], b[2];
            #pragma unroll
            for (int m = 0; m < 4; ++m) {
                const int r = wr * 64 + m * 16 + lrow;
                const int byte = (r * 128 + kk * 64 + lk * 16) ^ ((r & 7) << 4);
                a[m] = *reinterpret_cast<const short8*>((const char*)&Asm[cur][0] + byte);
            }
            #pragma unroll
            for (int n = 0; n < 2; ++n) {
                const int r = wc * 32 + n * 16 + lrow;
                const int byte = (r * 128 + kk * 64 + lk * 16) ^ ((r & 7) << 4);
                b[n] = *reinterpret_cast<const short8*>((const char*)&Bsm[cur][0] + byte);
            }
            #pragma unroll
            for (int m = 0; m < 4; ++m)
                #pragma unroll
                for (int n = 0; n < 2; ++n)
                    acc[m][n] = __builtin_amdgcn_mfma_f32_16x16x32_bf16(
                        a[m], b[n], acc[m][n], 0, 0, 0);
        }
        __builtin_amdgcn_sched_barrier(0);
        __builtin_amdgcn_s_barrier();
        __builtin_amdgcn_sched_barrier(0);
        if (it < 6) STAGE(cur, (it + 2) * 64);
    }
    #pragma unroll
    for (int n = 0; n < 2; ++n) {
        const int ocol = n0 + wc * 32 + n * 16 + lrow;
        #pragma unroll
        for (int m = 0; m < 4; ++m) {
            #pragma unroll
            for (int r = 0; r < 4; ++r) {
                const int orow = tok0 + wr * 64 + m * 16 + lk * 4 + r;
                float v = acc[m][n][r] + pb[n];
                if (MODE == 0) {
                    ((unsigned short*)outp)[(size_t)orow * 512 + ocol] = f2bf(v);
                } else {
                    v += rr[n][m][r];
                    ((float*)outp)[(size_t)orow * 512 + ocol] = v;
                }
            }
        }
    }
}

// ---------------- attention: 8 tok/block, 40KB LDS, 4 blocks/CU ----------------
// tf: 8 tok x 16 t x 256B = 32KB (contiguous 2KB streams per (t,instr)); qw 8KB.
// 32 threads/token: half = tid>>7 (4 heads each), t = tid&15.

__global__ __launch_bounds__(256) void k3_attn(
    const float* __restrict__ track, const unsigned short* __restrict__ qwb,
    unsigned short* __restrict__ wtfb)
{
    __shared__ __align__(16) char tfL[32768];   // [t][tk][16 ch], src-swizzled
    __shared__ __align__(16) char qwL[8192];    // [tk][64 ch], src-swizzled
    const int tid = threadIdx.x;
    const int hw = blockIdx.x;                  // 1024 blocks
    const int logical = (hw & 7) * 128 + (hw >> 3);   // XCD-chunked, bijective
    const int tok0 = logical * 8;
    const int b = tok0 >> 12;
    const int c0 = tok0 & 4095;

    // qw: 512 chunks (2/thread)
    #pragma unroll
    for (int i = 0; i < 2; ++i) {
        const int f = tid + i * 256;
        const int tk = f >> 6, ch = f & 63;
        gl_lds16(qwb + (size_t)(tok0 + tk) * 512 + ((ch ^ (tk & 7)) << 3),
                 qwL + f * 16);
    }
    // tf: 2048 chunks (8/thread); each wave-instr covers 1KB of a 2KB row-stream
    #pragma unroll
    for (int i = 0; i < 8; ++i) {
        const int f = tid + i * 256;
        const int t = f >> 7, tk = (f >> 4) & 7, ch = f & 15;
        const int s = (t + tk) & 7;
        gl_lds16(track + ((size_t)(b * 16 + t) * 4096 + (c0 + tk)) * 64 + ((ch ^ s) << 2),
                 tfL + f * 16);
    }
    asm volatile("s_waitcnt vmcnt(0)" ::: "memory");
    __builtin_amdgcn_s_barrier();
    __builtin_amdgcn_sched_barrier(0);

    const int half = tid >> 7;          // heads half*4..half*4+3
    const int tokg = (tid >> 4) & 7;    // token 0..7
    const int t = tid & 15;             // logits: slot t; PV: d-quad t
    const int lane = tid & 63;

    // cache tf row (t, tokg): 16 float4
    float4 tfr[16];
    {
        const int rb = t * 2048 + tokg * 256;
        const int s = (t + tokg) & 7;
        #pragma unroll
        for (int q = 0; q < 16; ++q)
            tfr[q] = *reinterpret_cast<const float4*>(tfL + rb + ((q ^ s) << 4));
    }
    // 4 head-logits + softmax weights
    float pw4[4];
    #pragma unroll
    for (int hh = 0; hh < 4; ++hh) {
        const int h = half * 4 + hh;
        float a = 0.f;
        #pragma unroll
        for (int qc = 0; qc < 8; ++qc) {
            const ushort8 qv = *reinterpret_cast<const ushort8*>(
                qwL + tokg * 1024 + (((h * 8 + qc) ^ (tokg & 7)) << 4));
            const float4 t0 = tfr[qc * 2], t1 = tfr[qc * 2 + 1];
            a += bf2f(qv[0])*t0.x + bf2f(qv[1])*t0.y + bf2f(qv[2])*t0.z + bf2f(qv[3])*t0.w
               + bf2f(qv[4])*t1.x + bf2f(qv[5])*t1.y + bf2f(qv[6])*t1.z + bf2f(qv[7])*t1.w;
        }
        float lg = a * 0.125f;          // 1/sqrt(64)
        float mx = lg;
        #pragma unroll
        for (int m = 1; m < 16; m <<= 1) mx = fmaxf(mx, __shfl_xor(mx, m, 64));
        const float ev = __expf(lg - mx);
        float sm = ev;
        #pragma unroll
        for (int m = 1; m < 16; m <<= 1) sm += __shfl_xor(sm, m, 64);
        pw4[hh] = ev / sm;
    }
    // PV: thread (half, tokg, dq=t) accumulates d=t*4..t*4+3 for 4 heads
    float o[4][4];
    #pragma unroll
    for (int hh = 0; hh < 4; ++hh)
        #pragma unroll
        for (int j = 0; j < 4; ++j) o[hh][j] = 0.f;
    #pragma unroll
    for (int tt = 0; tt < 16; ++tt) {
        const float4 tv = *reinterpret_cast<const float4*>(
            tfL + tt * 2048 + tokg * 256 + ((t ^ ((tt + tokg) & 7)) << 4));
        #pragma unroll
        for (int hh = 0; hh < 4; ++hh) {
            const float wt = __shfl(pw4[hh], (lane & 48) + tt, 64);
            o[hh][0] += wt * tv.x; o[hh][1] += wt * tv.y;
            o[hh][2] += wt * tv.z; o[hh][3] += wt * tv.w;
        }
    }
    const int token = tok0 + tokg;
    #pragma unroll
    for (int hh = 0; hh < 4; ++hh) {
        ushort4v ov;
        ov[0] = f2bf(o[hh][0]); ov[1] = f2bf(o[hh][1]);
        ov[2] = f2bf(o[hh][2]); ov[3] = f2bf(o[hh][3]);
        *reinterpret_cast<ushort4v*>(
            wtfb + (size_t)token * 512 + (half * 4 + hh) * 64 + t * 4) = ov;
    }
}

extern "C" void kernel_launch(void* const* d_in, const int* in_sizes, int n_in,
                              void* d_out, int out_size, void* d_ws, size_t ws_size,
                              hipStream_t stream) {
    const float* x      = (const float*)d_in[0];
    const float* track  = (const float*)d_in[1];
    const float* nscale = (const float*)d_in[2];
    const float* wq     = (const float*)d_in[3];
    const float* bq     = (const float*)d_in[4];
    const float* wk     = (const float*)d_in[5];
    // d_in[6] = bk: constant over t per head -> softmax-invariant, omitted exactly
    const float* wv     = (const float*)d_in[7];
    const float* bv     = (const float*)d_in[8];
    const float* wo     = (const float*)d_in[9];
    const float* bo     = (const float*)d_in[10];
    float* buf = (float*)d_out;

    char* ws = (char*)d_ws;
    unsigned short* xnb  = (unsigned short*)ws;                // 8 MB
    unsigned short* qwb  = (unsigned short*)(ws + 8388608);    // 8 MB
    unsigned short* wtfb = (unsigned short*)(ws + 16777216);   // 8 MB
    unsigned short* wqkT = (unsigned short*)(ws + 25165824);   // 512 KB
    unsigned short* wvoT = (unsigned short*)(ws + 25690112);   // 512 KB
    float* bqk = (float*)(ws + 26214400);                      // 2 KB
    float* bvo = (float*)(ws + 26216448);                      // 2 KB

    kprep<<<192 + NTOK / 4, 256, 0, stream>>>(x, nscale, wq, bq, wk, wv, bv, wo, bo,
                                              wqkT, bqk, wvoT, bvo, xnb);
    kG<0><<<512, 256, 0, stream>>>(xnb, wqkT, bqk, nullptr, qwb);
    k3_attn<<<NTOK / 8, 256, 0, stream>>>(track, qwb, wtfb);
    kG<1><<<512, 256, 0, stream>>>(wtfb, wvoT, bvo, x, buf);
}